// Round 5
// baseline (1569.578 us; speedup 1.0000x reference)
//
#include <hip/hip_runtime.h>
#include <hip/hip_bf16.h>
#include <math.h>

typedef unsigned short u16;
typedef unsigned int u32;
typedef short v8s __attribute__((ext_vector_type(8)));
typedef float v4f __attribute__((ext_vector_type(4)));

#define SCALE_F 0.11180339887498949f

__device__ __forceinline__ float bf2f(u16 x) {
    unsigned int u = ((unsigned int)x) << 16;
    return __builtin_bit_cast(float, u);
}
__device__ __forceinline__ u16 f2bf(float f) {
    unsigned int u = __builtin_bit_cast(unsigned int, f);
    unsigned int r = (u + 0x7FFFu + ((u >> 16) & 1u)) >> 16;
    return (u16)r;
}
__device__ __forceinline__ float scrub(float v) {
    return (fabsf(v) < 1e30f) ? v : 0.f;
}
__device__ __forceinline__ v8s zero8() {
    union { v8s v; short s[8]; } t;
#pragma unroll
    for (int i = 0; i < 8; i++) t.s[i] = 0;
    return t.v;
}

// 16B global -> LDS direct copy (lands at ldsBase + lane*16)
typedef __attribute__((address_space(3))) u32 lds_u32;
typedef const __attribute__((address_space(1))) u32 glb_u32;
__device__ __forceinline__ void async16(const void* g, void* l) {
    __builtin_amdgcn_global_load_lds((glb_u32*)g, (lds_u32*)l, 16, 0, 0);
}

// ---------------------------------------------------------------------------
// convX: f32 -> bf16 hi + lo split
// ---------------------------------------------------------------------------
__global__ void convX_kernel(const float* __restrict__ X, u16* __restrict__ Xh,
                             u16* __restrict__ Xl, int n)
{
    int i = (blockIdx.x * 256 + threadIdx.x) * 4;
    if (i >= n) return;
    float4 v = *(const float4*)(X + i);
    float a[4] = { v.x, v.y, v.z, v.w };
    u16 hi[4], lo[4];
#pragma unroll
    for (int j = 0; j < 4; j++) {
        hi[j] = f2bf(a[j]);
        lo[j] = f2bf(a[j] - bf2f(hi[j]));
    }
    *(uint2*)(Xh + i) = *(uint2*)hi;
    *(uint2*)(Xl + i) = *(uint2*)lo;
}

// ---------------------------------------------------------------------------
// convT: W f32 [K][N] -> WT bf16 [N][K]
// ---------------------------------------------------------------------------
__global__ __launch_bounds__(256) void convT_kernel(
    const float* __restrict__ W, u16* __restrict__ WT, int K, int N)
{
    __shared__ float t[32][33];
    int n0 = blockIdx.x * 32, k0 = blockIdx.y * 32;
    int tx = threadIdx.x & 31, ty = threadIdx.x >> 5;
    for (int i = ty; i < 32; i += 8) {
        int k = k0 + i, n = n0 + tx;
        t[i][tx] = (k < K && n < N) ? W[(size_t)k * N + n] : 0.f;
    }
    __syncthreads();
    for (int i = ty; i < 32; i += 8) {
        int n = n0 + i, k = k0 + tx;
        if (n < N && k < K) WT[(size_t)n * K + k] = f2bf(t[tx][i]);
    }
}

// ---------------------------------------------------------------------------
// xmean
// ---------------------------------------------------------------------------
__global__ void xmean_kernel(const float* __restrict__ X, float* __restrict__ Xm)
{
    int c = blockIdx.x * 256 + threadIdx.x;
    if (c >= 2560) return;
    int g = blockIdx.y;
    const float* base = X + (size_t)g * 32 * 2560 + c;
    float s = 0.f;
#pragma unroll 4
    for (int j = 0; j < 32; j++) s += base[(size_t)j * 2560];
    Xm[(size_t)g * 2560 + c] = s * (1.f / 32.f);
}

// ---------------------------------------------------------------------------
// gemmS: split-precision (bf16x3) small GEMM for kmean (M=64)
// ---------------------------------------------------------------------------
__global__ __launch_bounds__(256) void gemmS_kernel(
    const float* __restrict__ A, const float* __restrict__ B,
    const float* __restrict__ bias, int M, int N, int K, float* __restrict__ outf)
{
    __shared__ __align__(16) u16 Ah[64][32], Al[64][32];
    __shared__ __align__(16) u16 Bh[64][32], Bl[64][32];
    const int tid = threadIdx.x;
    const int bm = blockIdx.x * 64, bn = blockIdx.y * 64;
    const int w = tid >> 6, lane = tid & 63;
    const int quad = lane >> 4, l = lane & 15;
    v4f acc[4];
#pragma unroll
    for (int nt = 0; nt < 4; nt++)
#pragma unroll
        for (int r = 0; r < 4; r++) acc[nt][r] = 0.f;
    const int ar = tid >> 2, ak = (tid & 3) * 8;
    const int kr = tid >> 3, nc = (tid & 7) * 8;
    for (int k0 = 0; k0 < K; k0 += 32) {
        float4 a0 = *(const float4*)(A + (size_t)(bm + ar) * K + (k0 + ak));
        float4 a1 = *(const float4*)(A + (size_t)(bm + ar) * K + (k0 + ak) + 4);
        float4 b0 = *(const float4*)(B + (size_t)(k0 + kr) * N + (bn + nc));
        float4 b1 = *(const float4*)(B + (size_t)(k0 + kr) * N + (bn + nc) + 4);
        float av[8] = {a0.x,a0.y,a0.z,a0.w,a1.x,a1.y,a1.z,a1.w};
        float bv[8] = {b0.x,b0.y,b0.z,b0.w,b1.x,b1.y,b1.z,b1.w};
        __syncthreads();
#pragma unroll
        for (int j = 0; j < 8; j++) {
            u16 h = f2bf(av[j]);
            Ah[ar][ak + j] = h; Al[ar][ak + j] = f2bf(av[j] - bf2f(h));
            u16 g = f2bf(bv[j]);
            Bh[nc + j][kr] = g; Bl[nc + j][kr] = f2bf(bv[j] - bf2f(g));
        }
        __syncthreads();
        v8s ah = *(const v8s*)(&Ah[w * 16 + l][quad * 8]);
        v8s al = *(const v8s*)(&Al[w * 16 + l][quad * 8]);
#pragma unroll
        for (int nt = 0; nt < 4; nt++) {
            v8s bh = *(const v8s*)(&Bh[nt * 16 + l][quad * 8]);
            v8s bl = *(const v8s*)(&Bl[nt * 16 + l][quad * 8]);
            acc[nt] = __builtin_amdgcn_mfma_f32_16x16x32_bf16(ah, bh, acc[nt], 0, 0, 0);
            acc[nt] = __builtin_amdgcn_mfma_f32_16x16x32_bf16(ah, bl, acc[nt], 0, 0, 0);
            acc[nt] = __builtin_amdgcn_mfma_f32_16x16x32_bf16(al, bh, acc[nt], 0, 0, 0);
        }
    }
#pragma unroll
    for (int nt = 0; nt < 4; nt++) {
        int col = bn + nt * 16 + l;
        float bvs = bias[col];
#pragma unroll
        for (int r = 0; r < 4; r++) {
            int row = bm + w * 16 + quad * 4 + r;
            if (row < M) outf[(size_t)row * N + col] = scrub(acc[nt][r] + bvs);
        }
    }
}

// ---------------------------------------------------------------------------
// m1: M1T[(b*1024+h*32+blk)][k] = sum_d Wq[k][h*80+d]*km[(b<<5)+blk][h*80+d]
// ---------------------------------------------------------------------------
__global__ __launch_bounds__(256) void m1_kernel(
    const float* __restrict__ Wq, const float* __restrict__ km,
    u16* __restrict__ M1hT, u16* __restrict__ M1lT)
{
    __shared__ float Ws[64][81];
    __shared__ float Ks[32][80];
    int k0 = blockIdx.x * 64, h = blockIdx.y, b = blockIdx.z;
    int tid = threadIdx.x;
    for (int i = tid; i < 64 * 80; i += 256) {
        int kk = i / 80, dd = i - kk * 80;
        Ws[kk][dd] = Wq[(size_t)(k0 + kk) * 2560 + h * 80 + dd];
    }
    for (int i = tid; i < 32 * 80; i += 256) {
        int bl = i / 80, dd = i - bl * 80;
        Ks[bl][dd] = km[(size_t)((b << 5) + bl) * 2560 + h * 80 + dd];
    }
    __syncthreads();
    int kk = tid & 63, bq4 = tid >> 6;
    for (int bt = 0; bt < 8; bt++) {
        int blk = bt * 4 + bq4;
        float s = 0.f;
#pragma unroll 8
        for (int d = 0; d < 80; d++) s += Ws[kk][d] * Ks[blk][d];
        u16 hi = f2bf(s);
        size_t o = (size_t)(b * 1024 + h * 32 + blk) * 2560 + k0 + kk;
        M1hT[o] = hi;
        M1lT[o] = f2bf(s - bf2f(hi));
    }
}

__global__ void bias3_kernel(const float* __restrict__ bq, const float* __restrict__ km,
                             float* __restrict__ bias3)
{
    int i = blockIdx.x * 256 + threadIdx.x;
    if (i >= 2048) return;
    int b = i >> 10, hb = i & 1023, h = hb >> 5, blk = hb & 31;
    float s = 0.f;
    for (int d = 0; d < 80; d++) s += bq[h * 80 + d] * km[(size_t)((b << 5) + blk) * 2560 + h * 80 + d];
    bias3[i] = s;
}

// ---------------------------------------------------------------------------
// gemm128: m97-structure GEMM. C = act(sum_seg A_s[M,K] @ B_s[N,K]^T + bias).
// 128x128 tile, 4 waves, global_load_lds staging. M%128==0, K%32==0.
// N arbitrary (stores masked; B OOB rows must be readable slack!).
// Epilogues: outb bf16(ldc), outf f32(ldc), outT [bh][96][1024], outT2 [bh][96][32].
// ---------------------------------------------------------------------------
__global__ __launch_bounds__(256) void gemm128_kernel(
    const u16* __restrict__ A0, const u16* __restrict__ B0,
    const u16* __restrict__ A1, const u16* __restrict__ B1,
    const u16* __restrict__ A2, const u16* __restrict__ B2,
    const float* __restrict__ bias, int M, int N, int K, int act, int ldc,
    u16* __restrict__ outb, float* __restrict__ outf,
    u16* __restrict__ outT, u16* __restrict__ outT2)
{
    __shared__ __align__(16) u16 As[128][32];
    __shared__ __align__(16) u16 Bs[128][32];
    const int tid = threadIdx.x, w = tid >> 6, lane = tid & 63;
    const int quad = lane >> 4, l = lane & 15;
    const int bm = blockIdx.x * 128, bn = blockIdx.y * 128;
    const int wr = (w >> 1) * 64, wc = (w & 1) * 64;
    const int srow = lane >> 2, skoff = (lane & 3) * 8;

    v4f acc[4][4];
#pragma unroll
    for (int i = 0; i < 4; i++)
#pragma unroll
        for (int j = 0; j < 4; j++)
#pragma unroll
            for (int r = 0; r < 4; r++) acc[i][j][r] = 0.f;

    const u16* Alist[3] = { A0, A1, A2 };
    const u16* Blist[3] = { B0, B1, B2 };

    for (int seg = 0; seg < 3; seg++) {
        const u16* Ap = Alist[seg];
        if (!Ap) break;
        const u16* Bp = Blist[seg];
        for (int k0 = 0; k0 < K; k0 += 32) {
            async16(Ap + (size_t)(bm + w * 32 + srow) * K + k0 + skoff,      &As[w * 32][0]);
            async16(Ap + (size_t)(bm + w * 32 + 16 + srow) * K + k0 + skoff, &As[w * 32 + 16][0]);
            async16(Bp + (size_t)(bn + w * 32 + srow) * K + k0 + skoff,      &Bs[w * 32][0]);
            async16(Bp + (size_t)(bn + w * 32 + 16 + srow) * K + k0 + skoff, &Bs[w * 32 + 16][0]);
            __syncthreads();
            v8s af[4], bf[4];
#pragma unroll
            for (int i = 0; i < 4; i++) af[i] = *(const v8s*)(&As[wr + i * 16 + l][quad * 8]);
#pragma unroll
            for (int j = 0; j < 4; j++) bf[j] = *(const v8s*)(&Bs[wc + j * 16 + l][quad * 8]);
#pragma unroll
            for (int i = 0; i < 4; i++)
#pragma unroll
                for (int j = 0; j < 4; j++)
                    acc[i][j] = __builtin_amdgcn_mfma_f32_16x16x32_bf16(af[i], bf[j], acc[i][j], 0, 0, 0);
            __syncthreads();
        }
    }

#pragma unroll
    for (int j = 0; j < 4; j++) {
        int col = bn + wc + j * 16 + l;
        if (col < N) {
            float bvs = bias[col];
#pragma unroll
            for (int i = 0; i < 4; i++) {
#pragma unroll
                for (int r = 0; r < 4; r++) {
                    int row = bm + wr + i * 16 + quad * 4 + r;
                    float c = acc[i][j][r] + bvs;
                    if (act == 1) c = 0.5f * c * (1.0f + erff(c * 0.70710678118654752f));
                    c = scrub(c);
                    if (outf) outf[(size_t)row * ldc + col] = c;
                    if (outb) outb[(size_t)row * ldc + col] = f2bf(c);
                    if (outT) {
                        int bb = row >> 10, s = row & 1023;
                        int hh = col / 80, dd = col - hh * 80;
                        outT[((size_t)((bb << 5) + hh) * 96 + dd) * 1024 + s] = f2bf(c);
                    }
                    if (outT2) {
                        int bh = row >> 5, blk = row & 31;
                        outT2[((size_t)bh * 96 + col) * 32 + blk] = f2bf(c);
                    }
                }
            }
        }
    }
}

// padV: vtb rows 80..95 per bh: row 80 = 1.0, rest 0
__global__ void padv_kernel(u16* __restrict__ vt)
{
    int i = blockIdx.x * 256 + threadIdx.x;
    if (i >= 64 * 16 * 1024) return;
    int s = i & 1023, rr = (i >> 10) & 15, bh = i >> 14;
    vt[((size_t)bh * 96 + 80 + rr) * 1024 + s] = (rr == 0) ? (u16)0x3F80 : (u16)0;
}
// padV2: vct rows 80..95 per bh (32 cols)
__global__ void padv2_kernel(u16* __restrict__ vct)
{
    int i = blockIdx.x * 256 + threadIdx.x;
    if (i >= 64 * 16 * 32) return;
    int blk = i & 31, rr = (i >> 5) & 15, bh = i >> 9;
    vct[((size_t)bh * 96 + 80 + rr) * 32 + blk] = (rr == 0) ? (u16)0x3F80 : (u16)0;
}

// ---------------------------------------------------------------------------
// gather kernels: compression-MLP input = K/V + comp_pos
// ---------------------------------------------------------------------------
__global__ void gatherF_kernel(const u16* __restrict__ src, const float* __restrict__ pos,
                               u16* __restrict__ F)
{
    int row = blockIdx.y;
    int col = blockIdx.x * 256 + threadIdx.x;
    if (col >= 2560) return;
    int b = row >> 10, h = (row >> 5) & 31, blk = row & 31;
    int j = col / 80, d = col - j * 80;
    float v = bf2f(src[(size_t)(b * 1024 + blk * 32 + j) * 2560 + h * 80 + d]) + pos[col];
    F[(size_t)row * 2560 + col] = f2bf(v);
}
__global__ void gatherFT_kernel(const u16* __restrict__ vt, const float* __restrict__ pos,
                                u16* __restrict__ F)
{
    int row = blockIdx.y;
    int col = blockIdx.x * 256 + threadIdx.x;
    if (col >= 2560) return;
    int b = row >> 10, h = (row >> 5) & 31, blk = row & 31;
    int j = col / 80, d = col - j * 80;
    float v = bf2f(vt[((size_t)((b << 5) + h) * 96 + d) * 1024 + blk * 32 + j]) + pos[col];
    F[(size_t)row * 2560 + col] = f2bf(v);
}

// ---------------------------------------------------------------------------
// gates
// ---------------------------------------------------------------------------
__global__ __launch_bounds__(256) void gates_kernel(
    const u16* __restrict__ gh, const float* __restrict__ W2,
    const float* __restrict__ b2, float* __restrict__ gates)
{
    int w = threadIdx.x >> 6, lane = threadIdx.x & 63;
    int token = blockIdx.x * 4 + w;
    float s0 = 0.f, s1 = 0.f, s2 = 0.f;
    for (int i = lane; i < 1280; i += 64) {
        float g = bf2f(gh[(size_t)token * 1280 + i]);
        s0 += g * W2[i * 3 + 0];
        s1 += g * W2[i * 3 + 1];
        s2 += g * W2[i * 3 + 2];
    }
#pragma unroll
    for (int m = 1; m < 64; m <<= 1) {
        s0 += __shfl_xor(s0, m);
        s1 += __shfl_xor(s1, m);
        s2 += __shfl_xor(s2, m);
    }
    if (lane == 0) {
        gates[token * 3 + 0] = scrub(1.f / (1.f + expf(-(s0 + b2[0]))));
        gates[token * 3 + 1] = scrub(1.f / (1.f + expf(-(s1 + b2[1]))));
        gates[token * 3 + 2] = scrub(1.f / (1.f + expf(-(s2 + b2[2]))));
    }
}

// ---------------------------------------------------------------------------
// attn v3: 4 independent waves/block (qt = bx*4+wid), zero barriers.
// Direct exp (no online max — logits O(5), shift-invariant). Rank-based top-k.
// vct [bh][96][32] with ones row 80 gives compressed sums via MFMA.
// ---------------------------------------------------------------------------
__global__ __launch_bounds__(256, 4) void attn_kernel(
    const u16* __restrict__ qb, const u16* __restrict__ kbf,
    const u16* __restrict__ vt, const u16* __restrict__ kc,
    const u16* __restrict__ vct, const float* __restrict__ BSf,
    const float* __restrict__ gates, u16* __restrict__ comb, u16* __restrict__ combl)
{
    const int tid = threadIdx.x, wid = tid >> 6, lane = tid & 63;
    const int quad = lane >> 4, l = lane & 15;
    const int qt = blockIdx.x * 4 + wid, bh = blockIdx.y, b = bh >> 5, h = bh & 31;

    __shared__ float bsS[4][16][36];
    __shared__ __align__(16) u16 PwS[4][16][40];
    float (*bs)[36] = bsS[wid];
    u16 (*Pw)[40] = PwS[wid];

    // ---- top-16 block selection (rank-based, all lanes active) ----
    float mine[8];
    {
        const float* p = BSf + ((size_t)b << 20) + (size_t)(qt * 16 + l) * 1024 + h * 32 + quad * 8;
        float4 v0 = *(const float4*)p, v1 = *(const float4*)(p + 4);
        mine[0]=v0.x; mine[1]=v0.y; mine[2]=v0.z; mine[3]=v0.w;
        mine[4]=v1.x; mine[5]=v1.y; mine[6]=v1.z; mine[7]=v1.w;
        *(float4*)(&bs[l][quad * 8]) = v0;
        *(float4*)(&bs[l][quad * 8 + 4]) = v1;
    }
    int rank[8];
#pragma unroll
    for (int j = 0; j < 8; j++) rank[j] = 0;
#pragma unroll
    for (int c4 = 0; c4 < 4; c4++) {
        float4 o0 = *(const float4*)(&bs[l][c4 * 8]);
        float4 o1 = *(const float4*)(&bs[l][c4 * 8 + 4]);
        float o[8] = {o0.x,o0.y,o0.z,o0.w,o1.x,o1.y,o1.z,o1.w};
#pragma unroll
        for (int m = 0; m < 8; m++) {
            int gm = c4 * 8 + m;
#pragma unroll
            for (int j = 0; j < 8; j++) {
                int gj = quad * 8 + j;
                bool better = (o[m] > mine[j]) || (o[m] == mine[j] && gm < gj);
                rank[j] += better ? 1 : 0;
            }
        }
    }
    unsigned int pm = 0;
#pragma unroll
    for (int j = 0; j < 8; j++) if (rank[j] < 16) pm |= 1u << (quad * 8 + j);
    pm |= __shfl_xor(pm, 16);
    pm |= __shfl_xor(pm, 32);
    const unsigned int selm_l = pm;   // full 32-bit mask for query row l

    // ---- Q fragments ----
    v8s qfrag[3];
    {
        const u16* qrow = qb + (size_t)(b * 1024 + qt * 16 + l) * 2560 + h * 80;
#pragma unroll
        for (int c = 0; c < 3; c++) {
            if (c == 2 && quad >= 2) qfrag[c] = zero8();
            else qfrag[c] = *(const v8s*)(qrow + c * 32 + quad * 8);
        }
    }

    // ---- compressed branch ----
    v4f oc[6];
#pragma unroll
    for (int t = 0; t < 6; t++)
#pragma unroll
        for (int r = 0; r < 4; r++) oc[t][r] = 0.f;
    {
        v4f s0, s1;
#pragma unroll
        for (int r = 0; r < 4; r++) { s0[r] = 0.f; s1[r] = 0.f; }
#pragma unroll
        for (int c = 0; c < 3; c++) {
            v8s b0, b1;
            if (c == 2 && quad >= 2) { b0 = zero8(); b1 = zero8(); }
            else {
                b0 = *(const v8s*)(kc + (size_t)(bh * 32 + l) * 80 + c * 32 + quad * 8);
                b1 = *(const v8s*)(kc + (size_t)(bh * 32 + 16 + l) * 80 + c * 32 + quad * 8);
            }
            s0 = __builtin_amdgcn_mfma_f32_16x16x32_bf16(qfrag[c], b0, s0, 0, 0, 0);
            s1 = __builtin_amdgcn_mfma_f32_16x16x32_bf16(qfrag[c], b1, s1, 0, 0, 0);
        }
#pragma unroll
        for (int r = 0; r < 4; r++) {
            Pw[quad * 4 + r][l]      = f2bf(__expf(s0[r] * SCALE_F));
            Pw[quad * 4 + r][l + 16] = f2bf(__expf(s1[r] * SCALE_F));
        }
        v8s pa = *(const v8s*)(&Pw[l][quad * 8]);
#pragma unroll
        for (int t = 0; t < 6; t++) {
            v8s vfr = *(const v8s*)(vct + ((size_t)bh * 96 + t * 16 + l) * 32 + quad * 8);
            oc[t] = __builtin_amdgcn_mfma_f32_16x16x32_bf16(pa, vfr, oc[t], 0, 0, 0);
        }
    }

    // ---- flash loop (no online rescale) ----
    v4f aw[6], as_[6];
#pragma unroll
    for (int t = 0; t < 6; t++)
#pragma unroll
        for (int r = 0; r < 4; r++) { aw[t][r] = 0.f; as_[t][r] = 0.f; }

    const u16* vtp = vt + (size_t)bh * 96 * 1024;

    for (int kb = 0; kb < 32; kb++) {
        v4f s0, s1;
#pragma unroll
        for (int r = 0; r < 4; r++) { s0[r] = 0.f; s1[r] = 0.f; }
#pragma unroll
        for (int c = 0; c < 3; c++) {
            v8s k0f, k1f;
            if (c == 2 && quad >= 2) { k0f = zero8(); k1f = zero8(); }
            else {
                size_t base = (size_t)(b * 1024 + kb * 32) * 2560 + h * 80 + c * 32 + quad * 8;
                k0f = *(const v8s*)(kbf + base + (size_t)l * 2560);
                k1f = *(const v8s*)(kbf + base + (size_t)(16 + l) * 2560);
            }
            s0 = __builtin_amdgcn_mfma_f32_16x16x32_bf16(qfrag[c], k0f, s0, 0, 0, 0);
            s1 = __builtin_amdgcn_mfma_f32_16x16x32_bf16(qfrag[c], k1f, s1, 0, 0, 0);
        }
#pragma unroll
        for (int r = 0; r < 4; r++) {
            Pw[quad * 4 + r][l]      = f2bf(__expf(s0[r] * SCALE_F));
            Pw[quad * 4 + r][l + 16] = f2bf(__expf(s1[r] * SCALE_F));
        }
        v8s pwa = *(const v8s*)(&Pw[l][quad * 8]);
        v8s psa = ((selm_l >> kb) & 1u) ? pwa : zero8();
#pragma unroll
        for (int t = 0; t < 6; t++) {
            v8s vfr = *(const v8s*)(vtp + ((size_t)(t * 16 + l)) * 1024 + kb * 32 + quad * 8);
            aw[t]  = __builtin_amdgcn_mfma_f32_16x16x32_bf16(pwa, vfr, aw[t], 0, 0, 0);
            as_[t] = __builtin_amdgcn_mfma_f32_16x16x32_bf16(psa, vfr, as_[t], 0, 0, 0);
        }
    }

    // ---- row sums from ones-row tile (t=5 col 0 -> lane quad*16) ----
    float l_w[4], l_s[4], l_c[4];
#pragma unroll
    for (int r = 0; r < 4; r++) {
        l_w[r] = __shfl(aw[5][r], quad * 16);
        l_s[r] = __shfl(as_[5][r], quad * 16);
        l_c[r] = __shfl(oc[5][r], quad * 16);
    }

    // ---- gate-combine + split store ----
#pragma unroll
    for (int r = 0; r < 4; r++) {
        int token = b * 1024 + qt * 16 + quad * 4 + r;
        float g0 = gates[token * 3 + 0], g1 = gates[token * 3 + 1], g2 = gates[token * 3 + 2];
        float inv_w = 1.f / fmaxf(l_w[r], 1e-30f);
        float inv_s = 1.f / fmaxf(l_s[r], 1e-30f);
        float inv_c = 1.f / fmaxf(l_c[r], 1e-30f);
#pragma unroll
        for (int t = 0; t < 5; t++) {
            float val = g0 * (oc[t][r] * inv_c) + g1 * (as_[t][r] * inv_s) + g2 * (aw[t][r] * inv_w);
            val = scrub(val);
            u16 hi = f2bf(val);
            size_t o = (size_t)token * 2560 + h * 80 + t * 16 + l;
            comb[o] = hi;
            combl[o] = f2bf(val - bf2f(hi));
        }
    }
}

// ---------------------------------------------------------------------------
extern "C" void kernel_launch(void* const* d_in, const int* in_sizes, int n_in,
                              void* d_out, int out_size, void* d_ws, size_t ws_size,
                              hipStream_t stream)
{
    (void)in_sizes; (void)n_in; (void)out_size; (void)ws_size;

    const float* X   = (const float*)d_in[0];
    const float* Wq  = (const float*)d_in[1];
    const float* bq  = (const float*)d_in[2];
    const float* Wk  = (const float*)d_in[3];
    const float* bk  = (const float*)d_in[4];
    const float* Wv  = (const float*)d_in[5];
    const float* bv  = (const float*)d_in[6];
    const float* Wo  = (const float*)d_in[7];
    const float* bo  = (const float*)d_in[8];
    const float* pos = (const float*)d_in[9];
    const float* cW1 = (const float*)d_in[10];
    const float* cb1 = (const float*)d_in[11];
    const float* cW2 = (const float*)d_in[12];
    const float* cb2 = (const float*)d_in[13];
    const float* gW1 = (const float*)d_in[14];
    const float* gb1 = (const float*)d_in[15];
    const float* gW2 = (const float*)d_in[16];
    const float* gb2 = (const float*)d_in[17];

    char* ws = (char*)d_ws;
    size_t off = 0;
    auto alloc = [&](size_t bytes) -> void* {
        void* p = ws + off;
        off += (bytes + 255) & ~(size_t)255;
        return p;
    };
    u16*   Xh     = (u16*)  alloc(2048ull * 2560 * 2);       // live: whole run
    u16*   Xl     = (u16*)  alloc(2048ull * 2560 * 2);       // live: BS only
    u16*   WqT    = (u16*)  alloc(2560ull * 2560 * 2);
    u16*   WkT    = (u16*)  alloc(2560ull * 2560 * 2);
    u16*   WvT    = (u16*)  alloc(2560ull * 2560 * 2);
    u16*   WoT    = (u16*)  alloc(2560ull * 2560 * 2);
    u16*   gW1T   = (u16*)  alloc(1280ull * 2560 * 2);
    u16*   cW1T   = (u16*)  alloc(384ull * 2560 * 2);        // 320 + slack rows
    u16*   cW2T   = (u16*)  alloc(128ull * 320 * 2);         // 80 + slack rows
    float* Xm     = (float*)alloc(64ull * 2560 * 4);
    float* kmeanS = (float*)alloc(64ull * 2560 * 4);
    u16*   M1hT   = (u16*)  alloc(2048ull * 2560 * 2);       // -> qbuf after BS
    u16*   M1lT   = (u16*)  alloc(2048ull * 2560 * 2);       // -> combl after BS
    float* bias3  = (float*)alloc(2048ull * 4);
    u16*   kbf    = (u16*)  alloc(2048ull * 2560 * 2);
    u16*   vtb    = (u16*)  alloc(64ull * 96 * 1024 * 2);
    char*  R1     = (char*) alloc(12ull * 1024 * 1024);      // gh -> Fb+H1 -> combb
    u16*   gh     = (u16*)R1;
    u16*   Fb     = (u16*)R1;
    u16*   H1     = (u16*)(R1 + 10ull * 1024 * 1024);
    u16*   combb  = (u16*)R1;
    u16*   KC     = (u16*)  alloc(2048ull * 80 * 2);
    u16*   vct    = (u16*)  alloc(64ull * 96 * 32 * 2);
    float* gatesf = (float*)alloc(2048ull * 3 * 4);
    alloc(64 * 1024);                                        // OOB-read slack
    u16*   qbuf   = M1hT;    // overlay (M1 dead after BS GEMMs)
    u16*   combl  = M1lT;    // overlay
    float* BSf    = (float*)d_out;   // 8.4 MB, dead before final GEMM

    dim3 blk(256);
    // ---- conversions ----
    convX_kernel<<<2048 * 2560 / 4 / 256, blk, 0, stream>>>(X, Xh, Xl, 2048 * 2560);
    convT_kernel<<<dim3(80, 80), blk, 0, stream>>>(Wq, WqT, 2560, 2560);
    convT_kernel<<<dim3(80, 80), blk, 0, stream>>>(Wk, WkT, 2560, 2560);
    convT_kernel<<<dim3(80, 80), blk, 0, stream>>>(Wv, WvT, 2560, 2560);
    convT_kernel<<<dim3(80, 80), blk, 0, stream>>>(Wo, WoT, 2560, 2560);
    convT_kernel<<<dim3(40, 80), blk, 0, stream>>>(gW1, gW1T, 2560, 1280);
    convT_kernel<<<dim3(10, 80), blk, 0, stream>>>(cW1, cW1T, 2560, 320);
    convT_kernel<<<dim3(3, 10), blk, 0, stream>>>(cW2, cW2T, 320, 80);
    // ---- selection-score pipeline ----
    xmean_kernel<<<dim3(10, 64), blk, 0, stream>>>(X, Xm);
    gemmS_kernel<<<dim3(1, 40), blk, 0, stream>>>(Xm, Wk, bk, 64, 2560, 2560, kmeanS);
    m1_kernel<<<dim3(40, 32, 2), blk, 0, stream>>>(Wq, kmeanS, M1hT, M1lT);
    bias3_kernel<<<8, blk, 0, stream>>>(bq, kmeanS, bias3);
    for (int b = 0; b < 2; b++) {
        size_t ao = (size_t)b * 1024 * 2560;
        gemm128_kernel<<<dim3(8, 8), blk, 0, stream>>>(
            Xh + ao, M1hT + ao, Xl + ao, M1hT + ao, Xh + ao, M1lT + ao,
            bias3 + b * 1024, 1024, 1024, 2560, 0, 1024,
            nullptr, BSf + ((size_t)b << 20), nullptr, nullptr);
    }
    // ---- projections (M1 regions become qbuf/combl AFTER this point) ----
    gemm128_kernel<<<dim3(16, 20), blk, 0, stream>>>(Xh, WqT, nullptr, nullptr, nullptr, nullptr,
        bq, 2048, 2560, 2560, 0, 2560, qbuf, nullptr, nullptr, nullptr);
    gemm128_kernel<<<dim3(16, 20), blk, 0, stream>>>(Xh, WkT, nullptr, nullptr, nullptr, nullptr,
        bk, 2048, 2560, 2560, 0, 2560, kbf, nullptr, nullptr, nullptr);
    gemm128_kernel<<<dim3(16, 20), blk, 0, stream>>>(Xh, WvT, nullptr, nullptr, nullptr, nullptr,
        bv, 2048, 2560, 2560, 0, 2560, nullptr, nullptr, vtb, nullptr);
    padv_kernel<<<4096, blk, 0, stream>>>(vtb);
    gemm128_kernel<<<dim3(16, 10), blk, 0, stream>>>(Xh, gW1T, nullptr, nullptr, nullptr, nullptr,
        gb1, 2048, 1280, 2560, 1, 1280, gh, nullptr, nullptr, nullptr);
    gates_kernel<<<512, blk, 0, stream>>>(gh, gW2, gb2, gatesf);
    // ---- compression MLP (K then V) ----
    gatherF_kernel<<<dim3(10, 2048), blk, 0, stream>>>(kbf, pos, Fb);
    gemm128_kernel<<<dim3(16, 3), blk, 0, stream>>>(Fb, cW1T, nullptr, nullptr, nullptr, nullptr,
        cb1, 2048, 320, 2560, 1, 320, H1, nullptr, nullptr, nullptr);
    gemm128_kernel<<<dim3(16, 1), blk, 0, stream>>>(H1, cW2T, nullptr, nullptr, nullptr, nullptr,
        cb2, 2048, 80, 320, 0, 80, KC, nullptr, nullptr, nullptr);
    gatherFT_kernel<<<dim3(10, 2048), blk, 0, stream>>>(vtb, pos, Fb);
    gemm128_kernel<<<dim3(16, 3), blk, 0, stream>>>(Fb, cW1T, nullptr, nullptr, nullptr, nullptr,
        cb1, 2048, 320, 2560, 1, 320, H1, nullptr, nullptr, nullptr);
    gemm128_kernel<<<dim3(16, 1), blk, 0, stream>>>(H1, cW2T, nullptr, nullptr, nullptr, nullptr,
        cb2, 2048, 80, 320, 0, 80, nullptr, nullptr, nullptr, vct);
    padv2_kernel<<<128, blk, 0, stream>>>(vct);
    // ---- fused attention ----
    attn_kernel<<<dim3(16, 64), blk, 0, stream>>>(qbuf, kbf, vtb, KC, vct, BSf, gatesf, combb, combl);
    // ---- output projection (split comb for margin) ----
    gemm128_kernel<<<dim3(16, 20), blk, 0, stream>>>(combb, WoT, combl, WoT, nullptr, nullptr,
        bo, 2048, 2560, 2560, 0, 2560, nullptr, (float*)d_out, nullptr, nullptr);
}